// Round 2
// baseline (906.528 us; speedup 1.0000x reference)
//
#include <hip/hip_runtime.h>

#define N_NODES 50000
#define E_EDGES 800000
#define ETOT (E_EDGES + N_NODES)   // self-loops appended
#define IN_CH 128
#define HH 128                     // HEADS*HID
#define HEADS 4
#define HID 32
#define OUT_CH 32
#define NEG 0.2f

// ---------------- layer-1 GEMM: xw1 = x @ W1, + attention dots ----------------
__global__ void gemm1_kernel(const float* __restrict__ x,
                             const float* __restrict__ W1,
                             const float* __restrict__ att_s,
                             const float* __restrict__ att_d,
                             float* __restrict__ xw,
                             float* __restrict__ a1s,
                             float* __restrict__ a1d) {
    __shared__ float Wl[IN_CH * HH];   // 64 KiB
    int t = threadIdx.x;
    for (int i = t; i < IN_CH * HH; i += 256) Wl[i] = W1[i];
    __syncthreads();
    int r = t >> 7;        // 0/1: which of the 2 rows per iter
    int j = t & 127;       // output channel
    int h = j >> 5;        // head
    float asc = att_s[j];
    float adc = att_d[j];
    for (int rp = blockIdx.x; rp < N_NODES / 2; rp += gridDim.x) {
        int row = rp * 2 + r;
        const float* xr = x + (size_t)row * IN_CH;
        float acc = 0.f;
#pragma unroll 4
        for (int k = 0; k < IN_CH; ++k) acc = fmaf(xr[k], Wl[k * HH + j], acc);
        xw[(size_t)row * HH + j] = acc;
        float ps = acc * asc, pd = acc * adc;
        for (int off = 16; off; off >>= 1) {
            ps += __shfl_down(ps, off, 32);
            pd += __shfl_down(pd, off, 32);
        }
        if ((t & 31) == 0) {
            a1s[row * HEADS + h] = ps;
            a1d[row * HEADS + h] = pd;
        }
    }
}

// ---------------- layer-1 edge pass A: weights + denominators ----------------
__global__ void edge1_denom(const int* __restrict__ ei,
                            const float* __restrict__ a1s,
                            const float* __restrict__ a1d,
                            float* __restrict__ w1e,
                            float* __restrict__ denom1) {
    int e = blockIdx.x * blockDim.x + threadIdx.x;
    if (e >= ETOT) return;
    int s, d;
    if (e < E_EDGES) { s = ei[e]; d = ei[E_EDGES + e]; }
    else { s = e - E_EDGES; d = s; }
    const float4 as = *(const float4*)(a1s + s * 4);
    const float4 ad = *(const float4*)(a1d + d * 4);
    float4 w; float v;
    v = as.x + ad.x; v = v > 0.f ? v : NEG * v; w.x = __expf(v);
    v = as.y + ad.y; v = v > 0.f ? v : NEG * v; w.y = __expf(v);
    v = as.z + ad.z; v = v > 0.f ? v : NEG * v; w.z = __expf(v);
    v = as.w + ad.w; v = v > 0.f ? v : NEG * v; w.w = __expf(v);
    *(float4*)(w1e + e * 4) = w;
    atomicAdd(denom1 + d * 4 + 0, w.x);
    atomicAdd(denom1 + d * 4 + 1, w.y);
    atomicAdd(denom1 + d * 4 + 2, w.z);
    atomicAdd(denom1 + d * 4 + 3, w.w);
}

// ---------------- layer-1 edge pass B: scatter-aggregate messages ----------------
__global__ void edge1_agg(const int* __restrict__ ei,
                          const float* __restrict__ xw,
                          const float* __restrict__ w1e,
                          const float* __restrict__ denom1,
                          float* __restrict__ agg1) {
    long long gid = (long long)blockIdx.x * blockDim.x + threadIdx.x;
    if (gid >= (long long)ETOT * HH) return;
    int e = (int)(gid >> 7);
    int j = (int)(gid & 127);
    int s, d;
    if (e < E_EDGES) { s = ei[e]; d = ei[E_EDGES + e]; }
    else { s = e - E_EDGES; d = s; }
    int h = j >> 5;
    float alpha = w1e[e * 4 + h] / (denom1[d * 4 + h] + 1e-16f);
    atomicAdd(agg1 + (size_t)d * HH + j, xw[(size_t)s * HH + j] * alpha);
}

// ------ layer-2 GEMM: h = elu(agg1+b1); hw2 = h @ W2, + attention dots ------
__global__ void gemm2_kernel(const float* __restrict__ agg1,
                             const float* __restrict__ b1,
                             const float* __restrict__ W2,
                             const float* __restrict__ att_s,
                             const float* __restrict__ att_d,
                             float* __restrict__ hw2,
                             float* __restrict__ a2s,
                             float* __restrict__ a2d) {
    __shared__ float Wl[HH * OUT_CH];  // 16 KiB
    __shared__ float hs[8][HH];        // 4 KiB
    int t = threadIdx.x;
    for (int i = t; i < HH * OUT_CH; i += 256) Wl[i] = W2[i];
    __syncthreads();
    int nChunks = (N_NODES + 7) / 8;
    for (int ch = blockIdx.x; ch < nChunks; ch += gridDim.x) {
        int row0 = ch * 8;
        __syncthreads();
        for (int i = t; i < 8 * HH; i += 256) {
            int rr = i >> 7, jj = i & 127;
            int row = row0 + rr;
            if (row < N_NODES) {
                float v = agg1[(size_t)row * HH + jj] + b1[jj];
                hs[rr][jj] = v > 0.f ? v : (__expf(v) - 1.f);   // ELU
            }
        }
        __syncthreads();
        int r = t >> 5, o = t & 31;
        int row = row0 + r;
        if (row < N_NODES) {
            float acc = 0.f;
#pragma unroll 4
            for (int jj = 0; jj < HH; ++jj) acc = fmaf(hs[r][jj], Wl[jj * OUT_CH + o], acc);
            hw2[(size_t)row * OUT_CH + o] = acc;
            float ps = acc * att_s[o], pd = acc * att_d[o];
            for (int off = 16; off; off >>= 1) {
                ps += __shfl_down(ps, off, 32);
                pd += __shfl_down(pd, off, 32);
            }
            if (o == 0) { a2s[row] = ps; a2d[row] = pd; }
        }
    }
}

// ---------------- layer-2 edge pass A ----------------
__global__ void edge2_denom(const int* __restrict__ ei,
                            const float* __restrict__ a2s,
                            const float* __restrict__ a2d,
                            float* __restrict__ w2e,
                            float* __restrict__ denom2) {
    int e = blockIdx.x * blockDim.x + threadIdx.x;
    if (e >= ETOT) return;
    int s, d;
    if (e < E_EDGES) { s = ei[e]; d = ei[E_EDGES + e]; }
    else { s = e - E_EDGES; d = s; }
    float v = a2s[s] + a2d[d];
    v = v > 0.f ? v : NEG * v;
    float w = __expf(v);
    w2e[e] = w;
    atomicAdd(denom2 + d, w);
}

// ---------------- layer-2 edge pass B ----------------
__global__ void edge2_agg(const int* __restrict__ ei,
                          const float* __restrict__ hw2,
                          const float* __restrict__ w2e,
                          const float* __restrict__ denom2,
                          float* __restrict__ out) {
    long long gid = (long long)blockIdx.x * blockDim.x + threadIdx.x;
    if (gid >= (long long)ETOT * OUT_CH) return;
    int e = (int)(gid >> 5);
    int o = (int)(gid & 31);
    int s, d;
    if (e < E_EDGES) { s = ei[e]; d = ei[E_EDGES + e]; }
    else { s = e - E_EDGES; d = s; }
    float alpha = w2e[e] / (denom2[d] + 1e-16f);
    atomicAdd(out + (size_t)d * OUT_CH + o, hw2[(size_t)s * OUT_CH + o] * alpha);
}

// ---------------- init output with bias b2 ----------------
__global__ void init_out(const float* __restrict__ b2, float* __restrict__ out) {
    int i = blockIdx.x * blockDim.x + threadIdx.x;
    if (i < N_NODES * OUT_CH) out[i] = b2[i & 31];
}

extern "C" void kernel_launch(void* const* d_in, const int* in_sizes, int n_in,
                              void* d_out, int out_size, void* d_ws, size_t ws_size,
                              hipStream_t stream) {
    const float* x   = (const float*)d_in[0];
    const int*   ei  = (const int*)d_in[1];     // int32! (JAX x64 off; harness int->int32)
    const float* W1  = (const float*)d_in[2];
    const float* as1 = (const float*)d_in[3];
    const float* ad1 = (const float*)d_in[4];
    const float* b1  = (const float*)d_in[5];
    const float* W2  = (const float*)d_in[6];
    const float* as2 = (const float*)d_in[7];
    const float* ad2 = (const float*)d_in[8];
    const float* b2  = (const float*)d_in[9];
    float* out = (float*)d_out;
    float* ws  = (float*)d_ws;

    // workspace layout (floats), with lifetime-based reuse; peak 16.8M fl = 67.2 MB
    float* xw1    = ws;                 // [0, 6.4e6)        layer-1 features
    float* hw2    = ws;                 // reuse: xw1 dead after edge1_agg
    float* a1s    = ws + 6400000;       // [6.4e6, 6.6e6)
    float* a1d    = ws + 6600000;       // [6.6e6, 6.8e6)
    float* a2s    = ws + 6400000;       // reuse a1s region
    float* a2d    = ws + 6600000;       // reuse a1d region
    float* w1e    = ws + 6800000;       // [6.8e6, 10.2e6)
    float* w2e    = ws + 6800000;       // reuse w1e region
    float* denom1 = ws + 10200000;      // [10.2e6, 10.4e6)
    float* denom2 = ws + 10200000;      // reuse denom1 region
    float* agg1   = ws + 10400000;      // [10.4e6, 16.8e6)

    hipMemsetAsync(denom1, 0, (size_t)N_NODES * HEADS * sizeof(float), stream);
    hipMemsetAsync(agg1,   0, (size_t)N_NODES * HH    * sizeof(float), stream);

    init_out<<<(N_NODES * OUT_CH + 255) / 256, 256, 0, stream>>>(b2, out);

    gemm1_kernel<<<2048, 256, 0, stream>>>(x, W1, as1, ad1, xw1, a1s, a1d);
    edge1_denom<<<(ETOT + 255) / 256, 256, 0, stream>>>(ei, a1s, a1d, w1e, denom1);
    edge1_agg<<<(int)(((long long)ETOT * HH + 255) / 256), 256, 0, stream>>>(ei, xw1, w1e, denom1, agg1);

    // denom2 reuses denom1's region — clear AFTER edge1_agg consumed denom1.
    hipMemsetAsync(denom2, 0, (size_t)N_NODES * sizeof(float), stream);

    gemm2_kernel<<<2048, 256, 0, stream>>>(agg1, b1, W2, as2, ad2, hw2, a2s, a2d);
    edge2_denom<<<(ETOT + 255) / 256, 256, 0, stream>>>(ei, a2s, a2d, w2e, denom2);
    edge2_agg<<<(int)(((long long)ETOT * OUT_CH + 255) / 256), 256, 0, stream>>>(ei, hw2, w2e, denom2, out);
}

// Round 3
// 557.394 us; speedup vs baseline: 1.6264x; 1.6264x over previous
//
#include <hip/hip_runtime.h>

#define N_NODES 50000
#define E_EDGES 800000
#define ETOT (E_EDGES + N_NODES)   // self-loops appended
#define IN_CH 128
#define HH 128                     // HEADS*HID
#define HEADS 4
#define HID 32
#define OUT_CH 32
#define NEG 0.2f

// ================= CSR build =================
__global__ void init_deg(int* __restrict__ deg) {
    int i = blockIdx.x * blockDim.x + threadIdx.x;
    if (i < N_NODES) deg[i] = 1;   // self-loop
}

__global__ void count_deg(const int* __restrict__ ei, int* __restrict__ deg) {
    int e = blockIdx.x * blockDim.x + threadIdx.x;
    if (e < E_EDGES) atomicAdd(deg + ei[E_EDGES + e], 1);
}

__device__ __forceinline__ int block_incl_scan(int v, int t) {
    for (int off = 1; off < 64; off <<= 1) {
        int n = __shfl_up(v, off, 64);
        if ((t & 63) >= off) v += n;
    }
    __shared__ int wsum[4];
    if ((t & 63) == 63) wsum[t >> 6] = v;
    __syncthreads();
    int w = t >> 6;
    if (w > 0) {
        int add = 0;
        for (int k = 0; k < w; ++k) add += wsum[k];
        v += add;
    }
    __syncthreads();
    return v;
}

#define NCHUNK ((N_NODES + 255) / 256)   // 196

__global__ void scan_s1(const int* __restrict__ deg, int* __restrict__ rowptr,
                        int* __restrict__ partials) {
    int t = threadIdx.x;
    int i = blockIdx.x * 256 + t;
    int v = (i < N_NODES) ? deg[i] : 0;
    int s = block_incl_scan(v, t);
    if (i < N_NODES) rowptr[i + 1] = s;
    if (t == 255) partials[blockIdx.x] = s;
}

__global__ void scan_s2(int* __restrict__ partials) {
    int t = threadIdx.x;
    int v = (t < NCHUNK) ? partials[t] : 0;
    int s = block_incl_scan(v, t);
    if (t < NCHUNK) partials[t] = s;
}

__global__ void scan_s3(int* __restrict__ rowptr, const int* __restrict__ partials) {
    int i = blockIdx.x * blockDim.x + threadIdx.x;
    if (i == 0) rowptr[0] = 0;
    if (i < N_NODES) {
        int c = i >> 8;
        if (c > 0) rowptr[i + 1] += partials[c - 1];
    }
}

__global__ void init_cursor(const int* __restrict__ rowptr, int* __restrict__ cursor) {
    int i = blockIdx.x * blockDim.x + threadIdx.x;
    if (i < N_NODES) cursor[i] = rowptr[i];
}

__global__ void fill_csr(const int* __restrict__ ei, int* __restrict__ cursor,
                         int* __restrict__ csr_src) {
    int e = blockIdx.x * blockDim.x + threadIdx.x;
    if (e >= ETOT) return;
    int s, d;
    if (e < E_EDGES) { s = ei[e]; d = ei[E_EDGES + e]; }
    else { s = e - E_EDGES; d = s; }
    int pos = atomicAdd(cursor + d, 1);
    csr_src[pos] = s;
}

// ================= layer-1 GEMM + attention dots =================
__global__ void gemm1_kernel(const float* __restrict__ x,
                             const float* __restrict__ W1,
                             const float* __restrict__ att_s,
                             const float* __restrict__ att_d,
                             float* __restrict__ xw,
                             float* __restrict__ a1s,
                             float* __restrict__ a1d) {
    __shared__ float Wl[IN_CH * HH];   // 64 KiB
    int t = threadIdx.x;
    for (int i = t; i < IN_CH * HH; i += 256) Wl[i] = W1[i];
    __syncthreads();
    int r = t >> 7;
    int j = t & 127;
    int h = j >> 5;
    float asc = att_s[j];
    float adc = att_d[j];
    for (int rp = blockIdx.x; rp < N_NODES / 2; rp += gridDim.x) {
        int row = rp * 2 + r;
        const float* xr = x + (size_t)row * IN_CH;
        float acc = 0.f;
#pragma unroll 4
        for (int k = 0; k < IN_CH; ++k) acc = fmaf(xr[k], Wl[k * HH + j], acc);
        xw[(size_t)row * HH + j] = acc;
        float ps = acc * asc, pd = acc * adc;
        for (int off = 16; off; off >>= 1) {
            ps += __shfl_down(ps, off, 32);
            pd += __shfl_down(pd, off, 32);
        }
        if ((t & 31) == 0) {
            a1s[row * HEADS + h] = ps;
            a1d[row * HEADS + h] = pd;
        }
    }
}

// ================= layer-1 softmax denominators (per-node wave) =================
__global__ void denom1_csr(const int* __restrict__ rowptr, const int* __restrict__ csr_src,
                           const float* __restrict__ a1s, const float* __restrict__ a1d,
                           float* __restrict__ rden) {
    int t = threadIdx.x;
    int d = blockIdx.x * 4 + (t >> 6);
    if (d >= N_NODES) return;
    int l = t & 63;
    int h = l & 3, el = l >> 2;          // 16 edge slots x 4 heads
    float ad = a1d[d * 4 + h];
    int p0 = rowptr[d], p1 = rowptr[d + 1];
    float sum = 0.f;
    for (int p = p0 + el; p < p1; p += 16) {
        int s = csr_src[p];
        float v = a1s[s * 4 + h] + ad;
        v = v > 0.f ? v : NEG * v;
        sum += __expf(v);
    }
    for (int off = 4; off < 64; off <<= 1) sum += __shfl_xor(sum, off, 64);
    if (l < 4) rden[d * 4 + l] = 1.f / (sum + 1e-16f);
}

// ================= layer-1 gather-aggregate =================
__global__ void gather1(const int* __restrict__ rowptr, const int* __restrict__ csr_src,
                        const float* __restrict__ a1s, const float* __restrict__ a1d,
                        const float* __restrict__ rden,
                        const float* __restrict__ xw, float* __restrict__ agg) {
    int t = threadIdx.x;
    int d = blockIdx.x * 2 + (t >> 7);
    if (d >= N_NODES) return;
    int j = t & 127, h = j >> 5;
    float ad = a1d[d * 4 + h];
    float rd = rden[d * 4 + h];
    int p0 = rowptr[d], p1 = rowptr[d + 1];
    float acc = 0.f;
    for (int p = p0; p < p1; ++p) {
        int s = csr_src[p];
        float v = a1s[s * 4 + h] + ad;
        v = v > 0.f ? v : NEG * v;
        float w = __expf(v);
        acc = fmaf(w, xw[(size_t)s * HH + j], acc);
    }
    agg[(size_t)d * HH + j] = acc * rd;
}

// ====== layer-2 GEMM: h = elu(agg+b1); hw2 = h @ W2, + attention dots ======
__global__ void gemm2_kernel(const float* __restrict__ agg1,
                             const float* __restrict__ b1,
                             const float* __restrict__ W2,
                             const float* __restrict__ att_s,
                             const float* __restrict__ att_d,
                             float* __restrict__ hw2,
                             float* __restrict__ a2s,
                             float* __restrict__ a2d) {
    __shared__ float Wl[HH * OUT_CH];  // 16 KiB
    __shared__ float hs[8][HH];        // 4 KiB
    int t = threadIdx.x;
    for (int i = t; i < HH * OUT_CH; i += 256) Wl[i] = W2[i];
    __syncthreads();
    int nChunks = (N_NODES + 7) / 8;
    for (int ch = blockIdx.x; ch < nChunks; ch += gridDim.x) {
        int row0 = ch * 8;
        __syncthreads();
        for (int i = t; i < 8 * HH; i += 256) {
            int rr = i >> 7, jj = i & 127;
            int row = row0 + rr;
            if (row < N_NODES) {
                float v = agg1[(size_t)row * HH + jj] + b1[jj];
                hs[rr][jj] = v > 0.f ? v : (__expf(v) - 1.f);   // ELU
            }
        }
        __syncthreads();
        int r = t >> 5, o = t & 31;
        int row = row0 + r;
        if (row < N_NODES) {
            float acc = 0.f;
#pragma unroll 4
            for (int jj = 0; jj < HH; ++jj) acc = fmaf(hs[r][jj], Wl[jj * OUT_CH + o], acc);
            hw2[(size_t)row * OUT_CH + o] = acc;
            float ps = acc * att_s[o], pd = acc * att_d[o];
            for (int off = 16; off; off >>= 1) {
                ps += __shfl_down(ps, off, 32);
                pd += __shfl_down(pd, off, 32);
            }
            if (o == 0) { a2s[row] = ps; a2d[row] = pd; }
        }
    }
}

// ================= layer-2 denominators =================
__global__ void denom2_csr(const int* __restrict__ rowptr, const int* __restrict__ csr_src,
                           const float* __restrict__ a2s, const float* __restrict__ a2d,
                           float* __restrict__ rden2) {
    int t = threadIdx.x;
    int d = blockIdx.x * 4 + (t >> 6);
    if (d >= N_NODES) return;
    int l = t & 63;
    float ad = a2d[d];
    int p0 = rowptr[d], p1 = rowptr[d + 1];
    float sum = 0.f;
    for (int p = p0 + l; p < p1; p += 64) {
        int s = csr_src[p];
        float v = a2s[s] + ad;
        v = v > 0.f ? v : NEG * v;
        sum += __expf(v);
    }
    for (int off = 32; off; off >>= 1) sum += __shfl_xor(sum, off, 64);
    if (l == 0) rden2[d] = 1.f / (sum + 1e-16f);
}

// ================= layer-2 gather-aggregate (writes final out) =================
__global__ void gather2(const int* __restrict__ rowptr, const int* __restrict__ csr_src,
                        const float* __restrict__ a2s, const float* __restrict__ a2d,
                        const float* __restrict__ rden2,
                        const float* __restrict__ hw2, const float* __restrict__ b2,
                        float* __restrict__ out) {
    int t = threadIdx.x;
    int d = blockIdx.x * 4 + (t >> 6);
    if (d >= N_NODES) return;
    int l = t & 63;
    int o = l & 31, el = l >> 5;
    float ad = a2d[d];
    int p0 = rowptr[d], p1 = rowptr[d + 1];
    float acc = 0.f;
    for (int p = p0 + el; p < p1; p += 2) {
        int s = csr_src[p];
        float v = a2s[s] + ad;
        v = v > 0.f ? v : NEG * v;
        acc = fmaf(__expf(v), hw2[(size_t)s * OUT_CH + o], acc);
    }
    acc += __shfl_down(acc, 32, 64);
    if (el == 0) out[(size_t)d * OUT_CH + o] = acc * rden2[d] + b2[o];
}

extern "C" void kernel_launch(void* const* d_in, const int* in_sizes, int n_in,
                              void* d_out, int out_size, void* d_ws, size_t ws_size,
                              hipStream_t stream) {
    const float* x   = (const float*)d_in[0];
    const int*   ei  = (const int*)d_in[1];     // int32 (JAX x64 off)
    const float* W1  = (const float*)d_in[2];
    const float* as1 = (const float*)d_in[3];
    const float* ad1 = (const float*)d_in[4];
    const float* b1  = (const float*)d_in[5];
    const float* W2  = (const float*)d_in[6];
    const float* as2 = (const float*)d_in[7];
    const float* ad2 = (const float*)d_in[8];
    const float* b2  = (const float*)d_in[9];
    float* out = (float*)d_out;
    float* ws  = (float*)d_ws;

    // workspace layout (floats); peak 14.36M floats = 57.4 MB
    float* xw1    = ws;                        // 6,400,000 ; hw2 reuses
    float* hw2    = ws;
    float* agg1   = ws + 6400000;              // 6,400,000
    float* a1s    = ws + 12800000;             //   200,000 ; a2s reuses
    float* a1d    = ws + 13000000;             //   200,000 ; a2d reuses
    float* a2s    = a1s;
    float* a2d    = a1d;
    float* rden1  = ws + 13200000;             //   200,000 ; rden2 reuses
    float* rden2  = rden1;
    int*   deg    = (int*)(ws + 13400000);     //    50,000 (also cursor)
    int*   rowptr = (int*)(ws + 13450000);     //    50,016
    int*   parts  = (int*)(ws + 13500016);     //       256
    int*   csr_src= (int*)(ws + 13500272);     //   850,000  -> end 14,350,272

    // ---- CSR build (graph-only) ----
    init_deg   <<<(N_NODES + 255) / 256, 256, 0, stream>>>(deg);
    count_deg  <<<(E_EDGES + 255) / 256, 256, 0, stream>>>(ei, deg);
    scan_s1    <<<NCHUNK, 256, 0, stream>>>(deg, rowptr, parts);
    scan_s2    <<<1, 256, 0, stream>>>(parts);
    scan_s3    <<<(N_NODES + 255) / 256, 256, 0, stream>>>(rowptr, parts);
    init_cursor<<<(N_NODES + 255) / 256, 256, 0, stream>>>(rowptr, deg);
    fill_csr   <<<(ETOT + 255) / 256, 256, 0, stream>>>(ei, deg, csr_src);

    // ---- layer 1 ----
    gemm1_kernel<<<2048, 256, 0, stream>>>(x, W1, as1, ad1, xw1, a1s, a1d);
    denom1_csr <<<(N_NODES + 3) / 4, 256, 0, stream>>>(rowptr, csr_src, a1s, a1d, rden1);
    gather1    <<<(N_NODES + 1) / 2, 256, 0, stream>>>(rowptr, csr_src, a1s, a1d, rden1, xw1, agg1);

    // ---- layer 2 ----
    gemm2_kernel<<<2048, 256, 0, stream>>>(agg1, b1, W2, as2, ad2, hw2, a2s, a2d);
    denom2_csr <<<(N_NODES + 3) / 4, 256, 0, stream>>>(rowptr, csr_src, a2s, a2d, rden2);
    gather2    <<<(N_NODES + 3) / 4, 256, 0, stream>>>(rowptr, csr_src, a2s, a2d, rden2, hw2, b2, out);
}